// Round 8
// baseline (251.588 us; speedup 1.0000x reference)
//
#include <hip/hip_runtime.h>
#include <math.h>

#define BB 2
#define LL 2048
#define DD 1024
#define HH 16
#define DHD 64
#define NT (BB*LL)
#define D3 (3*DD)
#define D2 (2*DD)

typedef __bf16 bf16x8 __attribute__((ext_vector_type(8)));
typedef float  f32x4  __attribute__((ext_vector_type(4)));

__device__ __forceinline__ f32x4 mfma16(bf16x8 a, bf16x8 b, f32x4 c) {
    return __builtin_amdgcn_mfma_f32_16x16x32_bf16(a, b, c, 0, 0, 0);
}

__device__ __forceinline__ unsigned short f2bf(float f) {
    unsigned int u = __float_as_uint(f);
    u = (u + 0x7FFFu + ((u >> 16) & 1u)) >> 16;
    return (unsigned short)u;
}
__device__ __forceinline__ float bf2f(unsigned short s) {
    return __uint_as_float(((unsigned int)s) << 16);
}

__device__ __forceinline__ void gload16(const void* g, void* l) {
    __builtin_amdgcn_global_load_lds(
        (const __attribute__((address_space(1))) void*)g,
        (__attribute__((address_space(3))) void*)l, 16, 0, 0);
}

__device__ __forceinline__ float wred(float v) {
#pragma unroll
    for (int off = 32; off > 0; off >>= 1) v += __shfl_down(v, off, 64);
    return v;
}

// pack two positive fp32 -> bf16 pair (round-half-up) in 3 VALU ops
__device__ __forceinline__ unsigned int pack_bf2(float p0, float p1) {
    const unsigned int u0 = __float_as_uint(p0) + 0x8000u;
    const unsigned int u1 = __float_as_uint(p1) + 0x8000u;
    return __builtin_amdgcn_perm(u1, u0, 0x07060302u);  // [u1.hi16 : u0.hi16]
}

// -------------------- fused LayerNorm (blocks 0..NT-1) + weight cvt ----------
__global__ __launch_bounds__(256) void ln_cvt_kernel(
        const float* __restrict__ x, const float* __restrict__ w,
        const float* __restrict__ b, unsigned short* __restrict__ h,
        const float* __restrict__ wq, unsigned short* __restrict__ wqb,
        const float* __restrict__ wo, unsigned short* __restrict__ wob) {
    const int bx = blockIdx.x;
    const int tid = threadIdx.x;
    if (bx >= NT) {
        int i = (bx - NT) * 256 + tid;                    // 0..1048575 float4s
        const float* s; unsigned short* d;
        if (i < 786432) { s = wq; d = wqb; }
        else            { i -= 786432; s = wo; d = wob; }
        const float4 v = ((const float4*)s)[i];
        ((ushort4*)d)[i] = make_ushort4(f2bf(v.x), f2bf(v.y), f2bf(v.z), f2bf(v.w));
        return;
    }
    const float4 v = ((const float4*)(x + (size_t)bx * DD))[tid];
    float s = v.x + v.y + v.z + v.w;
    float ss = v.x*v.x + v.y*v.y + v.z*v.z + v.w*v.w;
    s = wred(s); ss = wred(ss);
    __shared__ float red[8];
    if ((tid & 63) == 0) { red[tid >> 6] = s; red[4 + (tid >> 6)] = ss; }
    __syncthreads();
    s  = red[0] + red[1] + red[2] + red[3];
    ss = red[4] + red[5] + red[6] + red[7];
    const float mu  = s * (1.0f / DD);
    const float inv = rsqrtf(ss * (1.0f / DD) - mu * mu + 1e-5f);
    const float4 wv = ((const float4*)w)[tid];
    const float4 bv = ((const float4*)b)[tid];
    *(ushort4*)(h + (size_t)bx * DD + tid * 4) = make_ushort4(
        f2bf((v.x - mu) * inv * wv.x + bv.x),
        f2bf((v.y - mu) * inv * wv.y + bv.y),
        f2bf((v.z - mu) * inv * wv.z + bv.z),
        f2bf((v.w - mu) * inv * wv.w + bv.w));
}

// -------------------- QKV GEMM: qk[t][2048] + V transposed to vt[B,H,DH,L] ----
__global__ __launch_bounds__(256) void gemm_qkv(
        const unsigned short* __restrict__ A, const unsigned short* __restrict__ B,
        unsigned short* __restrict__ qk, unsigned short* __restrict__ vt) {
    const int K = DD;
    __shared__ unsigned short As[128 * 32];
    __shared__ unsigned short Bs[128 * 32];
    const int tid = threadIdx.x;
    const int w = tid >> 6, lane = tid & 63;
    const int l15 = lane & 15, quad = lane >> 4;
    const int wr = w >> 1, wc = w & 1;
    const int m0 = blockIdx.y << 7, n0 = blockIdx.x << 7;

    const int srow = w * 32 + (lane >> 2);
    const int skel = (lane & 3) << 3;
    const unsigned short* gA = A + (size_t)(m0 + srow) * K + skel;
    const unsigned short* gB = B + (size_t)(n0 + srow) * K + skel;
    unsigned short* lA = &As[w * 1024];
    unsigned short* lB = &Bs[w * 1024];

    f32x4 acc[4][4];
#pragma unroll
    for (int i = 0; i < 4; i++)
#pragma unroll
        for (int j = 0; j < 4; j++) acc[i][j] = (f32x4){0.f, 0.f, 0.f, 0.f};

    for (int k0 = 0; k0 < K; k0 += 32) {
        gload16(gA + k0,                 lA);
        gload16(gA + k0 + (size_t)16*K,  lA + 512);
        gload16(gB + k0,                 lB);
        gload16(gB + k0 + (size_t)16*K,  lB + 512);
        __syncthreads();
        bf16x8 af[4], bg[4];
#pragma unroll
        for (int i = 0; i < 4; i++) {
            af[i] = *(const bf16x8*)&As[(wr*64 + i*16 + l15) * 32 + quad*8];
            bg[i] = *(const bf16x8*)&Bs[(wc*64 + i*16 + l15) * 32 + quad*8];
        }
#pragma unroll
        for (int i = 0; i < 4; i++)
#pragma unroll
            for (int j = 0; j < 4; j++)
                acc[i][j] = mfma16(af[i], bg[j], acc[i][j]);
        __syncthreads();
    }
    if (n0 < D2) {
#pragma unroll
        for (int i = 0; i < 4; i++) {
            const int mrow = m0 + wr*64 + i*16 + quad*4;
#pragma unroll
            for (int j = 0; j < 4; j++) {
                const int ncol = n0 + wc*64 + j*16 + l15;
#pragma unroll
                for (int r = 0; r < 4; r++)
                    qk[(size_t)(mrow + r) * D2 + ncol] = f2bf(acc[i][j][r]);
            }
        }
    } else {
#pragma unroll
        for (int i = 0; i < 4; i++) {
            const int mrow = m0 + wr*64 + i*16 + quad*4;
            const int bb = mrow >> 11, l = mrow & (LL - 1);
#pragma unroll
            for (int j = 0; j < 4; j++) {
                const int nv = n0 + wc*64 + j*16 + l15 - D2;
                const int hh = nv >> 6, dh = nv & 63;
                *(ushort4*)&vt[((size_t)(bb*HH + hh) * DHD + dh) * LL + l] =
                    make_ushort4(f2bf(acc[i][j][0]), f2bf(acc[i][j][1]),
                                 f2bf(acc[i][j][2]), f2bf(acc[i][j][3]));
            }
        }
    }
}

// -------------------- out-proj GEMM, 64x128 tile (2+ blocks/CU) ----------------
__global__ __launch_bounds__(256) void gemm_out(
        const unsigned short* __restrict__ A, const unsigned short* __restrict__ B,
        float* __restrict__ C, int M, int N, int K) {
    __shared__ unsigned short As[64 * 32];
    __shared__ unsigned short Bs[128 * 32];
    const int tid = threadIdx.x;
    const int w = tid >> 6, lane = tid & 63;
    const int l15 = lane & 15, quad = lane >> 4;
    const int wr = w >> 1, wc = w & 1;
    const int m0 = blockIdx.y << 6, n0 = blockIdx.x << 7;
    const int skel = (lane & 3) << 3;
    const unsigned short* gA = A + (size_t)(m0 + w*16 + (lane >> 2)) * K + skel;
    const unsigned short* gB = B + (size_t)(n0 + w*32 + (lane >> 2)) * K + skel;
    unsigned short* lA = &As[w * 512];
    unsigned short* lB = &Bs[w * 1024];
    f32x4 acc[2][4];
#pragma unroll
    for (int i = 0; i < 2; i++)
#pragma unroll
        for (int j = 0; j < 4; j++) acc[i][j] = (f32x4){0.f, 0.f, 0.f, 0.f};
    for (int k0 = 0; k0 < K; k0 += 32) {
        gload16(gA + k0,                 lA);
        gload16(gB + k0,                 lB);
        gload16(gB + k0 + (size_t)16*K,  lB + 512);
        __syncthreads();
        bf16x8 af[2], bg[4];
#pragma unroll
        for (int i = 0; i < 2; i++)
            af[i] = *(const bf16x8*)&As[(wr*32 + i*16 + l15) * 32 + quad*8];
#pragma unroll
        for (int j = 0; j < 4; j++)
            bg[j] = *(const bf16x8*)&Bs[(wc*64 + j*16 + l15) * 32 + quad*8];
#pragma unroll
        for (int i = 0; i < 2; i++)
#pragma unroll
            for (int j = 0; j < 4; j++)
                acc[i][j] = mfma16(af[i], bg[j], acc[i][j]);
        __syncthreads();
    }
#pragma unroll
    for (int i = 0; i < 2; i++) {
        const int mrow = m0 + wr*32 + i*16 + quad*4;
#pragma unroll
        for (int j = 0; j < 4; j++) {
            const int ncol = n0 + wc*64 + j*16 + l15;
#pragma unroll
            for (int r = 0; r < 4; r++)
                C[(size_t)(mrow + r) * N + ncol] = acc[i][j][r];
        }
    }
}

// -------------------- Q/K LayerNorm + NeoX RoPE: qk -> qarr/karr [B,H,L,DH] ----
__global__ __launch_bounds__(256) void qk_rope_kernel(
        const unsigned short* __restrict__ qk,
        const float* __restrict__ qw, const float* __restrict__ kw,
        unsigned short* __restrict__ qarr, unsigned short* __restrict__ karr) {
    const int t = blockIdx.x;
    const int l = t & (LL - 1), b = t >> 11;
    const int tid = threadIdx.x;
    const unsigned short* base = qk + (size_t)t * D2;
    const ushort4 qu = *(const ushort4*)(base + tid * 4);
    const ushort4 ku = *(const ushort4*)(base + DD + tid * 4);
    const float q[4] = {bf2f(qu.x), bf2f(qu.y), bf2f(qu.z), bf2f(qu.w)};
    const float k[4] = {bf2f(ku.x), bf2f(ku.y), bf2f(ku.z), bf2f(ku.w)};
    float sq = q[0]+q[1]+q[2]+q[3], ssq = q[0]*q[0]+q[1]*q[1]+q[2]*q[2]+q[3]*q[3];
    float sk = k[0]+k[1]+k[2]+k[3], ssk = k[0]*k[0]+k[1]*k[1]+k[2]*k[2]+k[3]*k[3];
    sq = wred(sq); ssq = wred(ssq); sk = wred(sk); ssk = wred(ssk);
    __shared__ float red[16];
    __shared__ float qs[DD], ks[DD];
    const int wid = tid >> 6;
    if ((tid & 63) == 0) { red[wid] = sq; red[4+wid] = ssq; red[8+wid] = sk; red[12+wid] = ssk; }
    __syncthreads();
    sq = red[0]+red[1]+red[2]+red[3];    ssq = red[4]+red[5]+red[6]+red[7];
    sk = red[8]+red[9]+red[10]+red[11];  ssk = red[12]+red[13]+red[14]+red[15];
    const float muq = sq * (1.f/DD), invq = rsqrtf(ssq*(1.f/DD) - muq*muq + 1e-5f);
    const float muk = sk * (1.f/DD), invk = rsqrtf(ssk*(1.f/DD) - muk*muk + 1e-5f);
    const float4 qwv = ((const float4*)qw)[tid];
    const float4 kwv = ((const float4*)kw)[tid];
    const float qwa[4] = {qwv.x, qwv.y, qwv.z, qwv.w};
    const float kwa[4] = {kwv.x, kwv.y, kwv.z, kwv.w};
    float qn[4], kn[4];
#pragma unroll
    for (int e = 0; e < 4; e++) {
        qn[e] = (q[e] - muq) * invq * qwa[e];
        kn[e] = (k[e] - muk) * invk * kwa[e];
    }
    *(float4*)&qs[tid*4] = make_float4(qn[0], qn[1], qn[2], qn[3]);
    *(float4*)&ks[tid*4] = make_float4(kn[0], kn[1], kn[2], kn[3]);
    __syncthreads();
    const int d = tid * 4, j0 = d & 63;
    const bool first = (j0 < 32);
    const int pt = first ? (tid + 8) : (tid - 8);
    const float4 qp4 = *(const float4*)&qs[pt*4];
    const float4 kp4 = *(const float4*)&ks[pt*4];
    const float qb[4] = {qp4.x, qp4.y, qp4.z, qp4.w};
    const float kb[4] = {kp4.x, kp4.y, kp4.z, kp4.w};
    const float lf = (float)l;
    const float QS = 0.125f * 1.44269504088896340736f;   // 1/sqrt(DH) * log2(e)
    unsigned short oq[4], ok[4];
#pragma unroll
    for (int e = 0; e < 4; e++) {
        const float fi   = (float)((j0 & 31) + e);
        const float frev = __builtin_amdgcn_exp2f(fi * -0.41524101186092029f)
                         * 0.15915494309189535f;
        float rev = lf * frev;
        rev -= floorf(rev);
        const float sn = __builtin_amdgcn_sinf(rev);   // sin(2*pi*rev)
        const float c  = __builtin_amdgcn_cosf(rev);   // cos(2*pi*rev)
        float vq, vk;
        if (first) { vq = qn[e]*c - qb[e]*sn; vk = kn[e]*c - kb[e]*sn; }
        else       { vq = qn[e]*c + qb[e]*sn; vk = kn[e]*c + kb[e]*sn; }
        oq[e] = f2bf(vq * QS);
        ok[e] = f2bf(vk);
    }
    const int hh = tid >> 4;
    const int dh = (tid * 4) & 63;
    const size_t ro = ((size_t)(b*HH + hh) * LL + l) * DHD + dh;
    *(ushort4*)(qarr + ro) = make_ushort4(oq[0], oq[1], oq[2], oq[3]);
    *(ushort4*)(karr + ro) = make_ushort4(ok[0], ok[1], ok[2], ok[3]);
}

// -------------------- MFMA flash attention: bpermute P-exchange, dbuf stage ----
// grid 1024: block = (bh, 64 q) x full kv via 2 kv-halves.
// 4 waves = (wq q-half 32) x (h kv-half 1024). 32-kv tiles, 32 iters, ONE
// barrier/iter (double-buffered K/V, stage kt+1 issued at body start).
// P relayout S^T-Clayout -> PV-A-layout done IN REGISTERS via ds_bpermute
// (lanes l15+16*q4, static idx) + cndmask: no Pw LDS, no store->load chain.
__global__ __launch_bounds__(256, 4) void attn_kernel(
        const unsigned short* __restrict__ qarr,
        const unsigned short* __restrict__ karr,
        const unsigned short* __restrict__ vt,
        unsigned short* __restrict__ ctxb) {
    const int x = blockIdx.x;
    const int bh = (x & 7) | ((x >> 8) << 3);   // 32 qblks of one head per XCD
    const int qblk = (x >> 3) & 31;
    const int b = bh >> 4, hh = bh & 15;
    const int q0 = qblk << 6;
    const int tid = threadIdx.x, w = tid >> 6, lane = tid & 63;
    const int l15 = lane & 15, quad = lane >> 4;
    const int h  = w & 1;           // kv half
    const int wq = w >> 1;          // q half (32 rows)

    __shared__ union {
        struct {
            unsigned short Ks[2][2][32 * 64];  // [half][buf][kv][dh] xor(row&7)
            unsigned short Vs[2][2][64 * 32];  // [half][buf][dh][kv] xor((row>>1)&3)
        } m;                                    // 32768 B
        struct {
            float red[64][68];                  // half-1 o dump (fp32)
            float lred[2][64];
            unsigned short red_bf[64][72];
        } e;                                    // 27136 B
    } sm;

    const unsigned short* kbase = karr + ((size_t)bh * LL + h * 1024) * DHD;
    const unsigned short* vbase = vt   + (size_t)bh * DHD * LL + h * 1024;

    // Q frags (B-operand): rows q0 + wq*32 + qt*16 + l15
    bf16x8 qf[2][2];
    {
        const unsigned short* qp = qarr + ((size_t)bh*LL + q0 + wq*32 + l15) * DHD + quad*8;
#pragma unroll
        for (int qt = 0; qt < 2; qt++)
#pragma unroll
            for (int c = 0; c < 2; c++)
                qf[qt][c] = *(const bf16x8*)(qp + qt*16*DHD + c*32);
    }

    f32x4 o[2][4];
    float lacc[2] = {0.f, 0.f};
#pragma unroll
    for (int qt = 0; qt < 2; qt++)
#pragma unroll
        for (int nt = 0; nt < 4; nt++) o[qt][nt] = (f32x4){0.f, 0.f, 0.f, 0.f};

    const int kr8 = lane >> 3, kc8 = lane & 7;   // K staging: 8 rows x 8 chunks
    const int vr4 = lane >> 2, vc4 = lane & 3;   // V staging: 16 rows x 4 chunks
    const int idxA = (l15 + 32*(quad & 1)) * 4;  // bpermute byte indices
    const int idxB = idxA + 64;

#define STAGE(KT, BUF)                                                              \
    {                                                                               \
        const int kt_ = (KT);                                                       \
        _Pragma("unroll")                                                           \
        for (int rd = 0; rd < 2; rd++) {                                            \
            const int row = wq*16 + rd*8 + kr8;                                     \
            gload16(kbase + (size_t)(kt_*32 + row) * DHD + ((kc8 ^ (row & 7)) << 3),\
                    &sm.m.Ks[h][BUF][(wq*16 + rd*8) * 64]);                         \
        }                                                                           \
        _Pragma("unroll")                                                           \
        for (int rv = 0; rv < 2; rv++) {                                            \
            const int row = wq*32 + rv*16 + vr4;                                    \
            gload16(vbase + (size_t)row * LL + kt_*32 + ((vc4 ^ ((row >> 1) & 3)) << 3),\
                    &sm.m.Vs[h][BUF][(wq*32 + rv*16) * 32]);                        \
        }                                                                           \
    }

    STAGE(0, 0);

    for (int kt = 0; kt < 32; kt++) {
        __syncthreads();                   // stage(kt) drained; prev reads done
        if (kt + 1 < 32) STAGE(kt + 1, (kt + 1) & 1);
        const int bb = kt & 1;

        bf16x8 kf[2][2], vf[4];
#pragma unroll
        for (int t = 0; t < 2; t++)
#pragma unroll
            for (int c = 0; c < 2; c++) {
                const int slot = (quad + c*4) ^ (l15 & 7);
                kf[t][c] = *(const bf16x8*)&sm.m.Ks[h][bb][(t*16 + l15) * 64 + slot*8];
            }
        {
            const int slotv = quad ^ ((l15 >> 1) & 3);
#pragma unroll
            for (int nt = 0; nt < 4; nt++)
                vf[nt] = *(const bf16x8*)&sm.m.Vs[h][bb][(nt*16 + l15) * 32 + slotv*8];
        }

#pragma unroll
        for (int qt = 0; qt < 2; qt++) {
            // S^T = K.Q^T - 64 (fixed softmax shift via C-init), kv tile 32
            f32x4 st[2];
#pragma unroll
            for (int t = 0; t < 2; t++) {
                f32x4 z = (f32x4){-64.f, -64.f, -64.f, -64.f};
                z = mfma16(kf[t][0], qf[qt][0], z);
                z = mfma16(kf[t][1], qf[qt][1], z);
                st[t] = z;
            }
            uint2 pk[2];
            float ps = 0.f;
#pragma unroll
            for (int t = 0; t < 2; t++) {
                const float p0 = __builtin_amdgcn_exp2f(st[t][0]);
                const float p1 = __builtin_amdgcn_exp2f(st[t][1]);
                const float p2 = __builtin_amdgcn_exp2f(st[t][2]);
                const float p3 = __builtin_amdgcn_exp2f(st[t][3]);
                ps += (p0 + p1) + (p2 + p3);
                pk[t].x = pack_bf2(p0, p1);
                pk[t].y = pack_bf2(p2, p3);
            }
            lacc[qt] += ps;
            // exchange to PV A-layout: dest (l15,quad) reg j <- lane l15+16*q4
            const int a0x = __builtin_amdgcn_ds_bpermute(idxA, (int)pk[0].x);
            const int a1x = __builtin_amdgcn_ds_bpermute(idxA, (int)pk[1].x);
            const int a0y = __builtin_amdgcn_ds_bpermute(idxA, (int)pk[0].y);
            const int a1y = __builtin_amdgcn_ds_bpermute(idxA, (int)pk[1].y);
            const int b0x = __builtin_amdgcn_ds_bpermute(idxB, (int)pk[0].x);
            const int b1x = __builtin_amdgcn_ds_bpermute(idxB, (int)pk[1].x);
            const int b0y = __builtin_amdgcn_ds_bpermute(idxB, (int)pk[0].y);
            const int b1y = __builtin_amdgcn_ds_bpermute(idxB, (int)pk[1].y);
            union { int u[4]; bf16x8 v; } ap;
            ap.u[0] = (quad < 2) ? a0x : a1x;
            ap.u[1] = (quad < 2) ? a0y : a1y;
            ap.u[2] = (quad < 2) ? b0x : b1x;
            ap.u[3] = (quad < 2) ? b0y : b1y;
#pragma unroll
            for (int nt = 0; nt < 4; nt++)
                o[qt][nt] = mfma16(ap.v, vf[nt], o[qt][nt]);
        }
    }
#undef STAGE

    // cross-quad l reduce
    float lq[2];
#pragma unroll
    for (int qt = 0; qt < 2; qt++) {
        float v = lacc[qt];
        v += __shfl_xor(v, 16);
        v += __shfl_xor(v, 32);
        lq[qt] = v;
    }

    // ---- in-block merge of the two kv halves ----
    __syncthreads();
    if (h == 1) {
#pragma unroll
        for (int qt = 0; qt < 2; qt++)
#pragma unroll
            for (int nt = 0; nt < 4; nt++)
#pragma unroll
                for (int r = 0; r < 4; r++)
                    sm.e.red[wq*32 + qt*16 + quad*4 + r][nt*16 + l15] = o[qt][nt][r];
    }
    if (quad == 0)
#pragma unroll
        for (int qt = 0; qt < 2; qt++)
            sm.e.lred[h][wq*32 + qt*16 + l15] = lq[qt];
    __syncthreads();
    if (h == 0) {
#pragma unroll
        for (int qt = 0; qt < 2; qt++) {
            float inv[4];
#pragma unroll
            for (int r = 0; r < 4; r++) {
                const int tok = wq*32 + qt*16 + quad*4 + r;
                inv[r] = 1.0f / (sm.e.lred[0][tok] + sm.e.lred[1][tok]);
            }
#pragma unroll
            for (int nt = 0; nt < 4; nt++)
#pragma unroll
                for (int r = 0; r < 4; r++) {
                    const int tok = wq*32 + qt*16 + quad*4 + r;
                    const float v = (o[qt][nt][r] + sm.e.red[tok][nt*16 + l15]) * inv[r];
                    sm.e.red_bf[tok][nt*16 + l15] = f2bf(v);
                }
        }
    }
    __syncthreads();
    // coalesced store: 64 tokens x 8 x 16B segments
#pragma unroll
    for (int i = 0; i < 2; i++) {
        const int idx = tid + 256*i;
        const int token = idx >> 3, ch = idx & 7;
        const uint4 vdat = *(const uint4*)&sm.e.red_bf[token][ch*8];
        *(uint4*)&ctxb[(size_t)(b*LL + q0 + token) * DD + hh*DHD + ch*8] = vdat;
    }
}

extern "C" void kernel_launch(void* const* d_in, const int* in_sizes, int n_in,
                              void* d_out, int out_size, void* d_ws, size_t ws_size,
                              hipStream_t stream) {
    const float* x      = (const float*)d_in[0];
    const float* ln_w   = (const float*)d_in[1];
    const float* ln_b   = (const float*)d_in[2];
    const float* w_qkv  = (const float*)d_in[3];
    const float* q_ln_w = (const float*)d_in[4];
    const float* k_ln_w = (const float*)d_in[5];
    const float* w_out  = (const float*)d_in[6];
    float* out = (float*)d_out;

    // workspace map (48 MB), lifetime-aliased:
    //  [0,8M)   h bf16 -> karr [B,H,L,DH] (rope; h dead after gemm_qkv)
    //  [8,24M)  qk bf16 [t][2048] -> ctx bf16 (attn; qk dead after rope)
    //  [24,32M) vt bf16 [B,H,DH,L]
    //  [32,40M) qarr bf16 [B,H,L,DH]
    //  [40,46M) wqb ; [46,48M) wob
    char* ws = (char*)d_ws;
    unsigned short* hb    = (unsigned short*)ws;
    unsigned short* karr  = (unsigned short*)ws;
    unsigned short* qk    = (unsigned short*)(ws + ((size_t)8  << 20));
    unsigned short* ctxb  = (unsigned short*)(ws + ((size_t)8  << 20));
    unsigned short* vtp   = (unsigned short*)(ws + ((size_t)24 << 20));
    unsigned short* qarr  = (unsigned short*)(ws + ((size_t)32 << 20));
    unsigned short* wqb   = (unsigned short*)(ws + ((size_t)40 << 20));
    unsigned short* wob   = (unsigned short*)(ws + ((size_t)46 << 20));

    ln_cvt_kernel<<<NT + 4096, 256, 0, stream>>>(x, ln_w, ln_b, hb,
                                                 w_qkv, wqb, w_out, wob);
    gemm_qkv<<<dim3(D3/128, NT/128), 256, 0, stream>>>(hb, wqb, qk, vtp);
    qk_rope_kernel<<<NT, 256, 0, stream>>>(qk, q_ln_w, k_ln_w, qarr, karr);
    attn_kernel<<<1024, 256, 0, stream>>>(qarr, karr, vtp, ctxb);
    gemm_out<<<dim3(DD/128, NT/64), 256, 0, stream>>>(ctxb, wob, out, NT, DD, DD);
}